// Round 3
// baseline (6776.842 us; speedup 1.0000x reference)
//
#include <hip/hip_runtime.h>
#include <math.h>

#define Hn 50
#define HP 56           // padded k extent (14 float4 chunks)
#define Dn 8
#define Tn 512
#define BB 8            // batch rows per block
#define CH 7            // float4 chunks per half (7*4 = 28 k's)
#define NBLK (2048 / BB)

__device__ __forceinline__ float sigmoidf_(float x) {
    return 1.0f / (1.0f + __expf(-x));
}
__device__ __forceinline__ float tanhf_(float x) {
    float a = fabsf(x);
    float e = __expf(-2.0f * a);
    float r = (1.0f - e) / (1.0f + e);
    return copysignf(r, x);
}

// Persistent 2-layer LSTM. 512 threads, 1 block/CU (launch_bounds(512,1)
// -> 256-VGPR budget so the 84-float weight slice NEVER spills; the
// round-2 regression was launch_bounds(512,2) capping VGPRs at 128 ->
// 11.5 GB of scratch write-through).
// half = tid>>8 owns k-chunks [half*7, half*7+7); rid = tid&255 is the
// padded gate row (gate = rid>>6, cell = rid&63, cells 50..63 padding).
// h-state is stored [b][k] (padded to 56, pad zeroed) so matvec reads are
// wave-uniform float4 broadcasts and activation writes are lane-stride-1.
__global__ __launch_bounds__(512, 1) void lstm2_kernel(
    const float* __restrict__ x,
    const float* __restrict__ Wih0, const float* __restrict__ Whh0,
    const float* __restrict__ bih0, const float* __restrict__ bhh0,
    const float* __restrict__ Wih1, const float* __restrict__ Whh1,
    const float* __restrict__ bih1, const float* __restrict__ bhh1,
    const float* __restrict__ Wlin, const float* __restrict__ blin,
    float* __restrict__ out)
{
    const int tid  = threadIdx.x;        // 0..511
    const int b0   = blockIdx.x * BB;
    const int half = tid >> 8;           // 0,1
    const int rid  = tid & 255;
    const int gate = rid >> 6;           // 0..3 (i,f,g,o)
    const int cell = rid & 63;           // 0..63 (50..63 padding)
    const bool real = (cell < Hn);
    const int grow = gate * Hn + cell;   // weight row (valid iff real)
    const int kbase = half * (CH * 4);   // 0 or 28

    __shared__ __align__(16) float h0s[BB][HP];
    __shared__ __align__(16) float h1s[BB][HP];
    __shared__ __align__(16) float gP[2][BB][256];  // [half][b][rid]
    __shared__ __align__(16) float xss[2][BB][Dn];  // double-buffered x_t

    // ---- per-thread weight slices in registers (28 k's x 3 matrices) ----
    float wa[CH * 4], wb[CH * 4], wc[CH * 4], wx[4];
    #pragma unroll
    for (int j = 0; j < CH * 4; ++j) {
        const int k = kbase + j;
        float va = 0.f, vb = 0.f, vc = 0.f;
        if (real && k < Hn) {
            va = Whh0[grow * Hn + k];
            vb = Wih1[grow * Hn + k];
            vc = Whh1[grow * Hn + k];
        }
        wa[j] = va; wb[j] = vb; wc[j] = vc;
    }
    #pragma unroll
    for (int d = 0; d < 4; ++d)
        wx[d] = real ? Wih0[grow * Dn + half * 4 + d] : 0.f;

    // ---- activation mapping: thread (bA, cellA) owns state (bA, cellA) ----
    const int bA    = tid >> 6;          // 0..7 (wave index)
    const int cellA = tid & 63;          // 0..63 (50..63 idle)
    const bool actT = (cellA < Hn);
    float bs0[4] = {0,0,0,0}, bs1[4] = {0,0,0,0};
    if (actT) {
        #pragma unroll
        for (int g = 0; g < 4; ++g) {
            bs0[g] = bih0[g * Hn + cellA] + bhh0[g * Hn + cellA];
            bs1[g] = bih1[g * Hn + cellA] + bhh1[g * Hn + cellA];
        }
    }
    float c0 = 0.f, c1 = 0.f;

    // zero h-state including pad columns (BB*HP = 448 floats each)
    if (tid < BB * HP) {
        ((float*)h0s)[tid] = 0.f;
        ((float*)h1s)[tid] = 0.f;
    }
    // stage x for t=0 (8 rows x 2 float4)
    if (tid < 16) {
        const int row = tid >> 1, part = tid & 1;
        const float4 v = *(const float4*)(x + (size_t)(b0 + row) * Tn * Dn
                                            + (size_t)part * 4);
        *(float4*)&xss[0][row][part * 4] = v;
    }
    __syncthreads();

    const bool pfT = (tid >= 498 && tid < 506);  // wave-7 padding lanes
    const int pfRow = tid - 498;

    for (int t = 0; t < Tn; ++t) {
        const int p = t & 1;

        // issue x(t+1) prefetch early
        float4 xp0, xp1;
        if (pfT && t + 1 < Tn) {
            const float* xr = x + (size_t)(b0 + pfRow) * Tn * Dn
                                + (size_t)(t + 1) * Dn;
            xp0 = *(const float4*)xr;
            xp1 = *(const float4*)(xr + 4);
        }

        // ---- phase 1: accA = wx.x_t + wa.h0 ; accC = wc.h1 (k-partials) ----
        float accA[BB], accC[BB];
        #pragma unroll
        for (int b = 0; b < BB; ++b) {
            const float4 xv = *(const float4*)&xss[p][b][half * 4];
            accA[b] = wx[0]*xv.x + wx[1]*xv.y + wx[2]*xv.z + wx[3]*xv.w;
            accC[b] = 0.f;
        }
        #pragma unroll
        for (int b = 0; b < BB; ++b) {
            #pragma unroll
            for (int c = 0; c < CH; ++c) {
                const float4 h0v = *(const float4*)&h0s[b][kbase + c * 4];
                const float4 h1v = *(const float4*)&h1s[b][kbase + c * 4];
                accA[b] += wa[c*4+0]*h0v.x + wa[c*4+1]*h0v.y
                         + wa[c*4+2]*h0v.z + wa[c*4+3]*h0v.w;
                accC[b] += wc[c*4+0]*h1v.x + wc[c*4+1]*h1v.y
                         + wc[c*4+2]*h1v.z + wc[c*4+3]*h1v.w;
            }
        }
        #pragma unroll
        for (int b = 0; b < BB; ++b) gP[half][b][rid] = accA[b];  // stride-1
        __syncthreads();

        // ---- layer-0 activations ----
        if (actT) {
            const float gi = gP[0][bA][      cellA] + gP[1][bA][      cellA] + bs0[0];
            const float gf = gP[0][bA][ 64 + cellA] + gP[1][bA][ 64 + cellA] + bs0[1];
            const float gg = gP[0][bA][128 + cellA] + gP[1][bA][128 + cellA] + bs0[2];
            const float go = gP[0][bA][192 + cellA] + gP[1][bA][192 + cellA] + bs0[3];
            const float iv = sigmoidf_(gi);
            const float fv = sigmoidf_(gf);
            const float gv = tanhf_(gg);
            const float ov = sigmoidf_(go);
            c0 = fv * c0 + iv * gv;
            h0s[bA][cellA] = ov * tanhf_(c0);   // lane-stride-1 write
        }
        __syncthreads();

        // ---- phase 2: accC += wb . h0_new ----
        #pragma unroll
        for (int b = 0; b < BB; ++b) {
            #pragma unroll
            for (int c = 0; c < CH; ++c) {
                const float4 h0v = *(const float4*)&h0s[b][kbase + c * 4];
                accC[b] += wb[c*4+0]*h0v.x + wb[c*4+1]*h0v.y
                         + wb[c*4+2]*h0v.z + wb[c*4+3]*h0v.w;
            }
        }
        #pragma unroll
        for (int b = 0; b < BB; ++b) gP[half][b][rid] = accC[b];
        __syncthreads();

        // ---- layer-1 activations + x(t+1) stage ----
        if (actT) {
            const float gi = gP[0][bA][      cellA] + gP[1][bA][      cellA] + bs1[0];
            const float gf = gP[0][bA][ 64 + cellA] + gP[1][bA][ 64 + cellA] + bs1[1];
            const float gg = gP[0][bA][128 + cellA] + gP[1][bA][128 + cellA] + bs1[2];
            const float go = gP[0][bA][192 + cellA] + gP[1][bA][192 + cellA] + bs1[3];
            const float iv = sigmoidf_(gi);
            const float fv = sigmoidf_(gf);
            const float gv = tanhf_(gg);
            const float ov = sigmoidf_(go);
            c1 = fv * c1 + iv * gv;
            h1s[bA][cellA] = ov * tanhf_(c1);
        }
        if (pfT && t + 1 < Tn) {
            *(float4*)&xss[(t + 1) & 1][pfRow][0] = xp0;
            *(float4*)&xss[(t + 1) & 1][pfRow][4] = xp1;
        }
        __syncthreads();
    }

    // ---- head: out[b] = h1_last . Wlin + blin ----
    if (tid < BB) {
        float o = blin[0];
        #pragma unroll
        for (int k = 0; k < Hn; ++k) o += Wlin[k] * h1s[tid][k];
        out[b0 + tid] = o;
    }
}

extern "C" void kernel_launch(void* const* d_in, const int* in_sizes, int n_in,
                              void* d_out, int out_size, void* d_ws, size_t ws_size,
                              hipStream_t stream) {
    const float* x    = (const float*)d_in[0];
    const float* Wih0 = (const float*)d_in[1];
    const float* Whh0 = (const float*)d_in[2];
    const float* bih0 = (const float*)d_in[3];
    const float* bhh0 = (const float*)d_in[4];
    const float* Wih1 = (const float*)d_in[5];
    const float* Whh1 = (const float*)d_in[6];
    const float* bih1 = (const float*)d_in[7];
    const float* bhh1 = (const float*)d_in[8];
    const float* Wlin = (const float*)d_in[9];
    const float* blin = (const float*)d_in[10];
    float* out = (float*)d_out;

    lstm2_kernel<<<NBLK, 512, 0, stream>>>(x, Wih0, Whh0, bih0, bhh0,
                                           Wih1, Whh1, bih1, bhh1,
                                           Wlin, blin, out);
}